// Round 4
// baseline (183.672 us; speedup 1.0000x reference)
//
#include <hip/hip_runtime.h>

// DSQG attention, J=12 causal offsets, f32.
// One 16-lane group per position; lane holds 4 channels (float4).
// R6: occupancy + rotation-parallelism experiment.
//   * Phased loads: batch A (q,12k,y,z,pb,pg) -> vmcnt(4) -> dot (k dies) ->
//     batch B (12v + vx) reuses k's registers -> DPP/softmax hides B ->
//     vmcnt(0). Peak ~96 VGPR, __launch_bounds__(256,4): tests whether the
//     37% occupancy plateau was register-limited.
//   * Lane-parallel rotation: lane grp handles offset pi=grp&7 (lanes 8-15
//     mirror 0-7 -> DPP 3-stage partial reduce is rotation-direction-proof).
//     Each lane: own z load, own phase_base/gain load, one extra L1-hot
//     float4 of row m[pi+4] ch0-3, e[4+pi] via 7-cndmask tree. Replaces the
//     ~200-slot serial grp==0 block (4/64 lanes) with ~40 full-width slots.
//     Invalid offsets self-kill: e[i]==0.
//   * se table in LDS, DPP 16-lane dot allreduce, max-free softmax, v_rcp.

namespace {

constexpr int J   = 12;
constexpr int B_  = 2;
constexpr int H_  = 16;
constexpr int N_  = 4096;
constexpr int HD_ = 64;
constexpr int OFFS[J] = {1, 2, 4, 8, 16, 64, 96, 192, 384, 512, 768, 1024};

using f32x4 = __attribute__((ext_vector_type(4))) float;
using f32x2 = __attribute__((ext_vector_type(2))) float;

#define GLOAD4(dst, off, base)                                              \
    asm volatile("global_load_dwordx4 %0, %1, %2"                           \
                 : "=v"(dst) : "v"(off), "s"(base) : "memory")
#define GLOAD2(dst, off, base)                                              \
    asm volatile("global_load_dwordx2 %0, %1, %2"                           \
                 : "=v"(dst) : "v"(off), "s"(base) : "memory")

// p += dpp_mov(p); CTRL must be an ICE, hence the template.
template <int CTRL>
__device__ __forceinline__ float dpp_add(float x) {
    int s = __builtin_amdgcn_update_dpp(0, __builtin_bit_cast(int, x),
                                        CTRL, 0xF, 0xF, false);
    return x + __builtin_bit_cast(float, s);
}

__global__ __launch_bounds__(256, 4) void dsqg_kernel(
    const float* __restrict__ q, const float* __restrict__ k,
    const float* __restrict__ v, const float* __restrict__ pb,
    const float* __restrict__ se, const float* __restrict__ phase_base,
    const float* __restrict__ phase_gain, const float* __restrict__ y_pre,
    const float* __restrict__ z_pre, float* __restrict__ out)
{
    __shared__ f32x4 seS[J * 16];     // 3 KB: se fragments, [i][grp]
    __shared__ int   dtab[8];         // OFFS[4..11] for per-lane lookup

    // XCD-locality swizzle: contiguous work range per XCD so k/v row re-reads
    // (reuse window <= 1024 rows = 512 KB) stay in that XCD's 4 MB L2.
    const int raw = blockIdx.x;
    const int per = gridDim.x >> 3;
    const int wid = (raw & 7) * per + (raw >> 3);

    const int bh    = wid >> 8;       // 256 blocks (16 positions each) per (b,h)
    const int chunk = wid & 255;
    const int h     = bh & (H_ - 1);

    const int tid  = threadIdx.x;
    const int lane = tid & 63;
    const int wave = tid >> 6;
    const int grp  = lane & 15;                        // lane within position group
    const int n    = chunk * 16 + wave * 4 + (lane >> 4);

    if (tid < J * 16) seS[tid] = ((const f32x4*)se)[tid];
    if (tid < 8)      dtab[tid] = OFFS[tid + 4];

    // uniform (SGPR) per-(b,h) base pointers; per-lane 32-bit byte offsets
    const size_t bhbytes = (size_t)bh * (N_ * HD_ * 4);
    const char* qb  = (const char*)q + bhbytes;
    const char* kb  = (const char*)k + bhbytes;
    const char* vb  = (const char*)v + bhbytes;
    char*       ob  = (char*)out + bhbytes;
    const char* yb  = (const char*)y_pre + (size_t)bh * (N_ * 8);
    const char* zb  = (const char*)z_pre + (size_t)bh * (N_ * 8);
    const char* pbb = (const char*)phase_base;
    const char* pgb = (const char*)phase_gain;

    const uint32_t gb   = (uint32_t)grp << 4;              // lane's float4 in a row
    const uint32_t rowb = ((uint32_t)n << 8) + gb;         // this position's slot
    const uint32_t nb8  = (uint32_t)n << 3;

    bool ok[J];
    uint32_t offb[J];                 // byte offset of k/v row slot (clamped)
#pragma unroll
    for (int i = 0; i < J; ++i) {
        ok[i]   = (n >= OFFS[i]);
        offb[i] = ok[i] ? (rowb - ((uint32_t)OFFS[i] << 8)) : gb;
    }

    __syncthreads();                  // seS/dtab ready; precedes the load batch

    // per-lane rotation parameters (lane handles offset index 4 + (grp&7))
    const int t8 = grp & 7;
    const int dl = dtab[t8];
    const bool okl = (n >= dl);
    const uint32_t zol  = okl ? (uint32_t)(n - dl) << 3 : 0u;   // z row (8 B)
    const uint32_t vxol = okl ? (uint32_t)(n - dl) << 8 : 0u;   // v row ch0-3
    const uint32_t pofs = (uint32_t)(t8 * H_ + h) << 3;         // [pi][h][2] f32

    // ---- batch A: q, 12 k, y, z, phase_base, phase_gain (17 loads) ----------
    f32x4 qr;
    GLOAD4(qr, rowb, qb);
    f32x4 kr[J];
#pragma unroll
    for (int i = 0; i < J; ++i) GLOAD4(kr[i], offb[i], kb);
    f32x2 yp;  GLOAD2(yp,  nb8,  yb);
    f32x2 zl;  GLOAD2(zl,  zol,  zb);
    f32x2 pbs; GLOAD2(pbs, pofs, pbb);
    f32x2 pgn; GLOAD2(pgn, pofs, pgb);

    asm volatile("s_waitcnt vmcnt(4)" ::: "memory");   // q + k complete
    __builtin_amdgcn_sched_barrier(0);

    // ---- partial dots: p_i = q . (k_i + se_i); k registers die here ---------
    float p[J];
#pragma unroll
    for (int i = 0; i < J; ++i) {
        const f32x4 seg = seS[i * 16 + grp];     // ds_read_b128, lgkm-managed
        float t = qr.x * (kr[i].x + seg.x);
        t = fmaf(qr.y, kr[i].y + seg.y, t);
        t = fmaf(qr.z, kr[i].z + seg.z, t);
        p[i] = fmaf(qr.w, kr[i].w + seg.w, t);
    }

    __builtin_amdgcn_sched_barrier(0);
    // ---- batch B: 12 v + vx (row m[4+t8] ch0-3), reusing k's registers ------
    f32x4 vr[J];
#pragma unroll
    for (int i = 0; i < J; ++i) GLOAD4(vr[i], offb[i], vb);
    f32x4 vx;
    GLOAD4(vx, vxol, vb);
    __builtin_amdgcn_sched_barrier(0);   // B pinned here; DPP/softmax follows

    // ---- 16-lane allreduce (pure VALU DPP); covers batch B latency ----------
#pragma unroll
    for (int i = 0; i < J; ++i) {
        p[i] = dpp_add<0xB1>(p[i]);    // quad_perm [1,0,3,2]  : xor 1
        p[i] = dpp_add<0x4E>(p[i]);    // quad_perm [2,3,0,1]  : xor 2
        p[i] = dpp_add<0x124>(p[i]);   // row_ror:4
        p[i] = dpp_add<0x128>(p[i]);   // row_ror:8
    }

    const float sc = 0.125f;  // 1/sqrt(64)
    float e[J];
    float sum = 0.f;
#pragma unroll
    for (int i = 0; i < J; ++i) {
        const float si = fmaf(p[i], sc, pb[i * H_ + h]);
        e[i] = ok[i] ? __expf(si) : 0.f;   // max-free: |si| ~ O(6), f32-safe
        sum += e[i];
    }

    asm volatile("s_waitcnt vmcnt(0)" ::: "memory");   // v, vx, y, z, pb, pg
    __builtin_amdgcn_sched_barrier(0);

    // ---- lane-parallel rotation: lane handles offset i = 4 + t8 -------------
    // e[4+t8] via 7-cndmask tree (no runtime array indexing -> no scratch)
    const float s01 = (t8 & 1) ? e[5]  : e[4];
    const float s23 = (t8 & 1) ? e[7]  : e[6];
    const float s45 = (t8 & 1) ? e[9]  : e[8];
    const float s67 = (t8 & 1) ? e[11] : e[10];
    const float sA  = (t8 & 2) ? s23 : s01;
    const float sB  = (t8 & 2) ? s67 : s45;
    const float esel = (t8 & 4) ? sB : sA;

    const float th0 = fmaf(pgn.x, yp.x * zl.x, pbs.x);
    const float th1 = fmaf(pgn.y, yp.y * zl.y, pbs.y);
    const float c0 = __cosf(th0), s0 = __sinf(th0);
    const float c1 = __cosf(th1), s1 = __sinf(th1);
    f32x4 cx;                                  // e_i * rotated(v ch0-3)
    cx.x = esel * (c0 * vx.x - s0 * vx.y);
    cx.y = esel * (s0 * vx.x + c0 * vx.y);
    cx.z = esel * (c1 * vx.z - s1 * vx.w);
    cx.w = esel * (s1 * vx.z + c1 * vx.w);

    // sum lanes 0..7 (lanes 8..15 mirror them, so ror:4 direction is moot):
    // xor1 + xor2 + ror4 -> every lane holds S = sum_{pi=0..7} cx_pi
#pragma unroll
    for (int st = 0; st < 1; ++st) { }         // (keep loop-free; stages below)
    cx.x = dpp_add<0xB1>(cx.x); cx.y = dpp_add<0xB1>(cx.y);
    cx.z = dpp_add<0xB1>(cx.z); cx.w = dpp_add<0xB1>(cx.w);
    cx.x = dpp_add<0x4E>(cx.x); cx.y = dpp_add<0x4E>(cx.y);
    cx.z = dpp_add<0x4E>(cx.z); cx.w = dpp_add<0x4E>(cx.w);
    cx.x = dpp_add<0x124>(cx.x); cx.y = dpp_add<0x124>(cx.y);
    cx.z = dpp_add<0x124>(cx.z); cx.w = dpp_add<0x124>(cx.w);

    // ---- weighted sum --------------------------------------------------------
    // lanes grp!=0: all 12 offsets unrotated (their channels are >= 4).
    // lane grp==0 (channels 0-3): offsets 0..3 unrotated + S (rotated 4..11).
    float4 accl = make_float4(0.f, 0.f, 0.f, 0.f);
#pragma unroll
    for (int i = 0; i < 4; ++i) {
        accl.x = fmaf(e[i], vr[i].x, accl.x);
        accl.y = fmaf(e[i], vr[i].y, accl.y);
        accl.z = fmaf(e[i], vr[i].z, accl.z);
        accl.w = fmaf(e[i], vr[i].w, accl.w);
    }
    float4 acch = accl;
#pragma unroll
    for (int i = 4; i < J; ++i) {
        acch.x = fmaf(e[i], vr[i].x, acch.x);
        acch.y = fmaf(e[i], vr[i].y, acch.y);
        acch.z = fmaf(e[i], vr[i].z, acch.z);
        acch.w = fmaf(e[i], vr[i].w, acch.w);
    }
    const bool lo = (grp == 0);
    float4 acc;
    acc.x = lo ? accl.x + cx.x : acch.x;
    acc.y = lo ? accl.y + cx.y : acch.y;
    acc.z = lo ? accl.z + cx.z : acch.z;
    acc.w = lo ? accl.w + cx.w : acch.w;

    float4 res;
    if (n >= 1) {                    // offset d=1 valid -> sum >= e[0] > 0
        const float inv = __builtin_amdgcn_rcpf(sum);   // ~1 ulp, tol is 2^-7
        res = make_float4(acc.x * inv, acc.y * inv, acc.z * inv, acc.w * inv);
    } else {                         // n==0: no valid offset -> zeros
        res = make_float4(0.f, 0.f, 0.f, 0.f);
    }
    *(float4*)(ob + rowb) = res;
}

} // namespace

extern "C" void kernel_launch(void* const* d_in, const int* in_sizes, int n_in,
                              void* d_out, int out_size, void* d_ws, size_t ws_size,
                              hipStream_t stream) {
    const float* q          = (const float*)d_in[0];
    const float* k          = (const float*)d_in[1];
    const float* v          = (const float*)d_in[2];
    const float* pb         = (const float*)d_in[3];
    const float* se         = (const float*)d_in[4];
    const float* phase_base = (const float*)d_in[5];
    const float* phase_gain = (const float*)d_in[6];
    const float* y_pre      = (const float*)d_in[7];
    const float* z_pre      = (const float*)d_in[8];
    float* out              = (float*)d_out;

    const int positions = B_ * H_ * N_;          // 131072
    const int blocks    = positions / 16;        // 16 positions per 256-thread block
    dsqg_kernel<<<blocks, 256, 0, stream>>>(q, k, v, pb, se, phase_base,
                                            phase_gain, y_pre, z_pre, out);
}

// Round 6
// 172.222 us; speedup vs baseline: 1.0665x; 1.0665x over previous
//
#include <hip/hip_runtime.h>

// DSQG attention, J=12 causal offsets, f32.
// R7b: identical design to R7 (round-5 bench died of an infra error, not a
// kernel fault — addresses audited in-bounds, vmcnt accounting verified).
// Cache-line-traffic cut. R6 post-mortem: occupancy +25% -> no speedup,
// VALU 29%, HBM 14% => bound by per-CU L1 line-fill throughput (~20 B/cy/CU;
// 850 MB of row traffic / 73 us matches). Fix = reduce lines:
//   * block owns 64 consecutive positions; k,v rows [P-16, P+63] (80 rows,
//     40 KB) staged to LDS once; offsets d in {1,2,4,8,16} (5 of 12) served
//     from LDS for BOTH the dot and the weighted sum. Removes the 5x re-read
//     of the small-offset window that L1 kept evicting.
//   * large offsets d in {64..1024} keep the R6 asm-batch structure:
//     batch A (q, 7 k, y, z) -> vmcnt(2) -> dot -> batch B (7 v + vx) ->
//     DPP reduce + softmax hides B -> vmcnt(0) -> rotation + sum.
//   * lane-parallel rotation (lane t8=grp&7 owns offset 4+t8), dl via
//     cndmask tree, se table in LDS, max-free softmax, v_rcp normalize.

namespace {

constexpr int J   = 12;
constexpr int B_  = 2;
constexpr int H_  = 16;
constexpr int N_  = 4096;
constexpr int HD_ = 64;
constexpr int OFFS[J] = {1, 2, 4, 8, 16, 64, 96, 192, 384, 512, 768, 1024};
constexpr int T_  = 64;   // positions per block
constexpr int W_  = 80;   // staged rows: [P-16, P+63]

using f32x4 = __attribute__((ext_vector_type(4))) float;
using f32x2 = __attribute__((ext_vector_type(2))) float;

#define GLOAD4(dst, off, base)                                              \
    asm volatile("global_load_dwordx4 %0, %1, %2"                           \
                 : "=v"(dst) : "v"(off), "s"(base) : "memory")
#define GLOAD2(dst, off, base)                                              \
    asm volatile("global_load_dwordx2 %0, %1, %2"                           \
                 : "=v"(dst) : "v"(off), "s"(base) : "memory")

// p += dpp_mov(p); CTRL must be an ICE, hence the template.
template <int CTRL>
__device__ __forceinline__ float dpp_add(float x) {
    int s = __builtin_amdgcn_update_dpp(0, __builtin_bit_cast(int, x),
                                        CTRL, 0xF, 0xF, false);
    return x + __builtin_bit_cast(float, s);
}

__global__ __launch_bounds__(256, 3) void dsqg_kernel(
    const float* __restrict__ q, const float* __restrict__ k,
    const float* __restrict__ v, const float* __restrict__ pb,
    const float* __restrict__ se, const float* __restrict__ phase_base,
    const float* __restrict__ phase_gain, const float* __restrict__ y_pre,
    const float* __restrict__ z_pre, float* __restrict__ out)
{
    __shared__ f32x4 kS[W_ * 16];     // 20 KB: k rows [P-16, P+63]
    __shared__ f32x4 vS[W_ * 16];     // 20 KB: v rows [P-16, P+63]
    __shared__ f32x4 seS[J * 16];     //  3 KB: se fragments [i][grp]

    // XCD-locality swizzle: contiguous work range per XCD.
    const int raw = blockIdx.x;
    const int per = gridDim.x >> 3;            // 2048/8 = 256
    const int wid = (raw & 7) * per + (raw >> 3);

    const int bh  = wid >> 6;                  // 64 blocks per (b,h)
    const int blk = wid & 63;
    const int h   = bh & (H_ - 1);
    const int P   = blk * T_;                  // first position of this block

    const int tid  = threadIdx.x;
    const int lane = tid & 63;
    const int wave = tid >> 6;
    const int grp  = lane & 15;                // lane within position group
    const int sub  = lane >> 4;                // position-within-quad

    if (tid < J * 16) seS[tid] = ((const f32x4*)se)[tid];

    // uniform (SGPR) per-(b,h) base pointers
    const size_t bhbytes = (size_t)bh * (N_ * HD_ * 4);
    const char* qb = (const char*)q + bhbytes;
    const char* kb = (const char*)k + bhbytes;
    const char* vb = (const char*)v + bhbytes;
    char*       ob = (char*)out + bhbytes;
    const char* yb = (const char*)y_pre + (size_t)bh * (N_ * 8);
    const char* zb = (const char*)z_pre + (size_t)bh * (N_ * 8);

    // ---- stage k/v window into LDS (coalesced; 5 iters x 256 thr x 16 B) ----
    {
        const int r0 = P - 16;
#pragma unroll
        for (int t = 0; t < (W_ * 16) / 256; ++t) {
            const int idx = t * 256 + tid;     // 0..1279 (float4 index)
            const int row = idx >> 4;
            const int col = idx & 15;
            int gr = r0 + row;                 // clamp for block 0 only
            gr = gr < 0 ? 0 : gr;
            const uint32_t go = ((uint32_t)gr << 8) + ((uint32_t)col << 4);
            kS[idx] = *(const f32x4*)(kb + go);
            vS[idx] = *(const f32x4*)(vb + go);
        }
    }

    // hoisted per-lane rotation offset dl = OFFS[4 + (grp&7)] via tree
    const int t8  = grp & 7;
    const int d01 = (t8 & 1) ? 64   : 16;
    const int d23 = (t8 & 1) ? 192  : 96;
    const int d45 = (t8 & 1) ? 512  : 384;
    const int d67 = (t8 & 1) ? 1024 : 768;
    const int dA  = (t8 & 2) ? d23 : d01;
    const int dB  = (t8 & 2) ? d67 : d45;
    const int dl  = (t8 & 4) ? dB : dA;

    const uint32_t pofs = (uint32_t)(t8 * H_ + h) << 3;    // [pi][h][2] f32
    const f32x2 pbs = *(const f32x2*)((const char*)phase_base + pofs);
    const f32x2 pgn = *(const f32x2*)((const char*)phase_gain + pofs);
    float pbh[J];
#pragma unroll
    for (int i = 0; i < J; ++i) pbh[i] = pb[i * H_ + h];   // uniform s_loads

    __syncthreads();    // staging + seS visible (compiler drains cnts first)

    const float sc = 0.125f;  // 1/sqrt(64)

#pragma unroll
    for (int j = 0; j < 4; ++j) {
        const int n = P + wave * 16 + j * 4 + sub;
        const uint32_t rowb = ((uint32_t)n << 8) + ((uint32_t)grp << 4);
        const uint32_t nb8  = (uint32_t)n << 3;

        bool ok[J];
#pragma unroll
        for (int i = 0; i < J; ++i) ok[i] = (n >= OFFS[i]);

        uint32_t offb[7];                    // large offsets d in {64..1024}
#pragma unroll
        for (int i = 5; i < J; ++i)
            offb[i - 5] = ok[i] ? (rowb - ((uint32_t)OFFS[i] << 8))
                                : ((uint32_t)grp << 4);

        const bool okl = (n >= dl);
        const uint32_t zol  = okl ? (uint32_t)(n - dl) << 3 : 0u;
        const uint32_t vxol = okl ? (uint32_t)(n - dl) << 8 : 0u;

        // ---- batch A: q, 7 large-d k, y, z (10 asm loads) ------------------
        f32x4 qr;
        GLOAD4(qr, rowb, qb);
        f32x4 kr[7];
#pragma unroll
        for (int i = 0; i < 7; ++i) GLOAD4(kr[i], offb[i], kb);
        f32x2 yp; GLOAD2(yp, nb8, yb);
        f32x2 zl; GLOAD2(zl, zol, zb);

        asm volatile("s_waitcnt vmcnt(2)" ::: "memory");   // q + k complete
        __builtin_amdgcn_sched_barrier(0);

        // ---- dots: small-d from LDS, large-d from regs ---------------------
        float p[J];
#pragma unroll
        for (int i = 0; i < 5; ++i) {
            const int rel = n - OFFS[i] - P + 16;          // in [8, 80)
            const f32x4 kk  = kS[rel * 16 + grp];
            const f32x4 seg = seS[i * 16 + grp];
            float t = qr.x * (kk.x + seg.x);
            t = fmaf(qr.y, kk.y + seg.y, t);
            t = fmaf(qr.z, kk.z + seg.z, t);
            p[i] = fmaf(qr.w, kk.w + seg.w, t);
        }
#pragma unroll
        for (int i = 5; i < J; ++i) {
            const f32x4 kk  = kr[i - 5];
            const f32x4 seg = seS[i * 16 + grp];
            float t = qr.x * (kk.x + seg.x);
            t = fmaf(qr.y, kk.y + seg.y, t);
            t = fmaf(qr.z, kk.z + seg.z, t);
            p[i] = fmaf(qr.w, kk.w + seg.w, t);
        }

        __builtin_amdgcn_sched_barrier(0);
        // ---- batch B: 7 large-d v + vx (reuses k's registers) --------------
        f32x4 vr[7];
#pragma unroll
        for (int i = 0; i < 7; ++i) GLOAD4(vr[i], offb[i], vb);
        f32x4 vx;
        GLOAD4(vx, vxol, vb);
        __builtin_amdgcn_sched_barrier(0);

        // ---- 16-lane allreduce (pure VALU DPP); covers batch B -------------
#pragma unroll
        for (int i = 0; i < J; ++i) {
            p[i] = dpp_add<0xB1>(p[i]);    // quad_perm [1,0,3,2] : xor 1
            p[i] = dpp_add<0x4E>(p[i]);    // quad_perm [2,3,0,1] : xor 2
            p[i] = dpp_add<0x124>(p[i]);   // row_ror:4
            p[i] = dpp_add<0x128>(p[i]);   // row_ror:8
        }

        float e[J];
        float sum = 0.f;
#pragma unroll
        for (int i = 0; i < J; ++i) {
            const float si = fmaf(p[i], sc, pbh[i]);
            e[i] = ok[i] ? __expf(si) : 0.f;   // max-free: |si| ~ O(6)
            sum += e[i];
        }

        asm volatile("s_waitcnt vmcnt(0)" ::: "memory");   // v, vx, y, z
        __builtin_amdgcn_sched_barrier(0);

        // ---- lane-parallel rotation: lane handles offset i = 4 + t8 --------
        const float s01 = (t8 & 1) ? e[5]  : e[4];
        const float s23 = (t8 & 1) ? e[7]  : e[6];
        const float s45 = (t8 & 1) ? e[9]  : e[8];
        const float s67 = (t8 & 1) ? e[11] : e[10];
        const float sA  = (t8 & 2) ? s23 : s01;
        const float sB  = (t8 & 2) ? s67 : s45;
        const float esel = (t8 & 4) ? sB : sA;

        const float th0 = fmaf(pgn.x, yp.x * zl.x, pbs.x);
        const float th1 = fmaf(pgn.y, yp.y * zl.y, pbs.y);
        const float c0 = __cosf(th0), s0 = __sinf(th0);
        const float c1 = __cosf(th1), s1 = __sinf(th1);
        f32x4 cx;                              // e_i * rotated(v ch0-3)
        cx.x = esel * (c0 * vx.x - s0 * vx.y);
        cx.y = esel * (s0 * vx.x + c0 * vx.y);
        cx.z = esel * (c1 * vx.z - s1 * vx.w);
        cx.w = esel * (s1 * vx.z + c1 * vx.w);

        // lanes 8-15 mirror 0-7 -> xor1+xor2+ror4 gives full 8-offset sum
        cx.x = dpp_add<0xB1>(cx.x);  cx.y = dpp_add<0xB1>(cx.y);
        cx.z = dpp_add<0xB1>(cx.z);  cx.w = dpp_add<0xB1>(cx.w);
        cx.x = dpp_add<0x4E>(cx.x);  cx.y = dpp_add<0x4E>(cx.y);
        cx.z = dpp_add<0x4E>(cx.z);  cx.w = dpp_add<0x4E>(cx.w);
        cx.x = dpp_add<0x124>(cx.x); cx.y = dpp_add<0x124>(cx.y);
        cx.z = dpp_add<0x124>(cx.z); cx.w = dpp_add<0x124>(cx.w);

        // ---- weighted sum: i<5 from LDS, i>=5 from regs --------------------
        float4 accl = make_float4(0.f, 0.f, 0.f, 0.f);
#pragma unroll
        for (int i = 0; i < 4; ++i) {
            const int rel = n - OFFS[i] - P + 16;
            const f32x4 vv = vS[rel * 16 + grp];
            accl.x = fmaf(e[i], vv.x, accl.x);
            accl.y = fmaf(e[i], vv.y, accl.y);
            accl.z = fmaf(e[i], vv.z, accl.z);
            accl.w = fmaf(e[i], vv.w, accl.w);
        }
        float4 acch = accl;
        {   // i = 4 (d = 16) from LDS
            const int rel = n - 16 - P + 16;
            const f32x4 vv = vS[rel * 16 + grp];
            acch.x = fmaf(e[4], vv.x, acch.x);
            acch.y = fmaf(e[4], vv.y, acch.y);
            acch.z = fmaf(e[4], vv.z, acch.z);
            acch.w = fmaf(e[4], vv.w, acch.w);
        }
#pragma unroll
        for (int i = 5; i < J; ++i) {
            acch.x = fmaf(e[i], vr[i - 5].x, acch.x);
            acch.y = fmaf(e[i], vr[i - 5].y, acch.y);
            acch.z = fmaf(e[i], vr[i - 5].z, acch.z);
            acch.w = fmaf(e[i], vr[i - 5].w, acch.w);
        }
        const bool lo = (grp == 0);
        float4 acc;
        acc.x = lo ? accl.x + cx.x : acch.x;
        acc.y = lo ? accl.y + cx.y : acch.y;
        acc.z = lo ? accl.z + cx.z : acch.z;
        acc.w = lo ? accl.w + cx.w : acch.w;

        float4 res;
        if (n >= 1) {                 // offset d=1 valid -> sum >= e[0] > 0
            const float inv = __builtin_amdgcn_rcpf(sum);  // tol is 2^-7
            res = make_float4(acc.x * inv, acc.y * inv, acc.z * inv, acc.w * inv);
        } else {                      // n==0: no valid offset -> zeros
            res = make_float4(0.f, 0.f, 0.f, 0.f);
        }
        *(float4*)(ob + rowb) = res;
    }
}

} // namespace

extern "C" void kernel_launch(void* const* d_in, const int* in_sizes, int n_in,
                              void* d_out, int out_size, void* d_ws, size_t ws_size,
                              hipStream_t stream) {
    const float* q          = (const float*)d_in[0];
    const float* k          = (const float*)d_in[1];
    const float* v          = (const float*)d_in[2];
    const float* pb         = (const float*)d_in[3];
    const float* se         = (const float*)d_in[4];
    const float* phase_base = (const float*)d_in[5];
    const float* phase_gain = (const float*)d_in[6];
    const float* y_pre      = (const float*)d_in[7];
    const float* z_pre      = (const float*)d_in[8];
    float* out              = (float*)d_out;

    const int positions = B_ * H_ * N_;          // 131072
    const int blocks    = positions / T_;        // 2048 blocks, 64 pos each
    dsqg_kernel<<<blocks, 256, 0, stream>>>(q, k, v, pb, se, phase_base,
                                            phase_gain, y_pre, z_pre, out);
}